// Round 2
// baseline (249.960 us; speedup 1.0000x reference)
//
#include <hip/hip_runtime.h>
#include <hip/hip_bf16.h>
#include <math.h>

// Problem constants: B=32 V=512 K=16 D=128 E=32 NE=8192 -> BV=16384 vertices
#define NLSTR 136   // LDS row stride (ushorts) for 16x128 tiles; 272B rows keep b128 reads spread

typedef __bf16 bf16x8 __attribute__((ext_vector_type(8)));
typedef float f32x4 __attribute__((ext_vector_type(4)));
typedef unsigned short ushort8v __attribute__((ext_vector_type(8)));

union FragU { ushort8v u; bf16x8 b; };

static __device__ inline unsigned short f2bf(float f){
  unsigned u = __float_as_uint(f);
  u += 0x7fffu + ((u >> 16) & 1u);   // RNE
  return (unsigned short)(u >> 16);
}

// tanh-form GELU via sigmoid: x * sigmoid(1.59577(x + 0.044715 x^3))
static __device__ inline float gelu_f(float x){
  float u = x * x;
  float p = fmaf(u, 0.07135481283f, 1.5957691216f);  // 1.59577*(1 + 0.044715 x^2)/x-factored
  float t = x * p;
  float e = __builtin_amdgcn_exp2f(t * -1.44269504f);
  return x * __builtin_amdgcn_rcpf(1.0f + e);
}

// ---------------- prep: bf16 vertex table + fragment-order bf16 weights ----------------
// w?f layout: frag (kc*8+nc) is 64 lanes x 8 elems contiguous: [((kc*8+nc)*64+lane)*8+j]
//   element j of lane (quad*16+col) = W[(nc*16+col)*rowlen + kc*32 + quad*8 + j]
__global__ __launch_bounds__(256) void prep_kernel(
    const float* __restrict__ vf, const float* __restrict__ W1,
    const float* __restrict__ W2, const float* __restrict__ W3,
    unsigned short* __restrict__ vfbf, unsigned short* __restrict__ w1f,
    unsigned short* __restrict__ w2f, unsigned short* __restrict__ w3f)
{
  int t = blockIdx.x * 256 + threadIdx.x;
  if (t < 262144){                       // 16384*128 / 8
    const float4* src = (const float4*)vf;
    float4 x = src[t * 2], y = src[t * 2 + 1];
    ushort8v o;
    o[0]=f2bf(x.x); o[1]=f2bf(x.y); o[2]=f2bf(x.z); o[3]=f2bf(x.w);
    o[4]=f2bf(y.x); o[5]=f2bf(y.y); o[6]=f2bf(y.z); o[7]=f2bf(y.w);
    *(ushort8v*)(vfbf + t * 8) = o;
    return;
  }
  int t2 = t - 262144;
  const float* W; unsigned short* O; int rowlen;
  if (t2 < 2560)      { W = W1; O = w1f; rowlen = 160; }             // 5kc x 8nc
  else if (t2 < 6656) { t2 -= 2560; W = W2; O = w2f; rowlen = 256; } // 8kc x 8nc
  else if (t2 < 8704) { t2 -= 6656; W = W3; O = w3f; rowlen = 128; } // 4kc x 8nc
  else return;
  int fragid = t2 >> 6, lane = t2 & 63;
  int kc = fragid >> 3, nc = fragid & 7, col = lane & 15, quad = lane >> 4;
  const float* s = W + (nc * 16 + col) * rowlen + kc * 32 + quad * 8;
  unsigned short* d = O + t2 * 8;
#pragma unroll
  for (int j = 0; j < 8; j++) d[j] = f2bf(s[j]);
}

// ---------------- fused: gather + W1 GEMM + GELU + K-sum + W2 + support + W3 + combine ----
// grid 1024 x 256thr. Block = 16 vertices. Stage1: wave wid owns vertices wid*4..wid*4+3
// (2 per iteration). Stage2: all 4 waves N-split the 128 output columns (2 nc-chunks each).
__global__ __launch_bounds__(256, 4) void fused_kernel(
    const unsigned short* __restrict__ vfbf, const float* __restrict__ vf,
    const int* __restrict__ aadj, const int* __restrict__ badj,
    const float* __restrict__ edge, const float* __restrict__ nbs,
    const float* __restrict__ h0,
    const unsigned short* __restrict__ w1f, const unsigned short* __restrict__ w2f,
    const unsigned short* __restrict__ w3f,
    const float* __restrict__ b1, const float* __restrict__ b2, const float* __restrict__ b3,
    const float* __restrict__ lamda, const float* __restrict__ alpha,
    const int* __restrict__ lval,
    float* __restrict__ out)
{
  __shared__ __align__(16) unsigned short nl_lds[16 * NLSTR];
  __shared__ __align__(16) unsigned short sup_lds[16 * NLSTR];
  const int wid  = threadIdx.x >> 6;
  const int lane = threadIdx.x & 63;
  const int col  = lane & 15;
  const int quad = lane >> 4;
  const int v0   = blockIdx.x * 16;

  float b1v[8];
#pragma unroll
  for (int nc = 0; nc < 8; nc++) b1v[nc] = b1[nc * 16 + col];

  // ---------------- stage 1 ----------------
  for (int it = 0; it < 2; ++it){
    const int vA = v0 + wid * 4 + it * 2;      // this wave's vertex pair
    // neighbor indices (lane col = neighbor row m; replicated across quads)
    const int a0 = aadj[vA * 16 + col];
    const int a1 = aadj[(vA + 1) * 16 + col];
    const int e0 = badj[vA * 16 + col];
    const int e1 = badj[(vA + 1) * 16 + col];
    const float4 mk0 = ((const float4*)(nbs + vA * 16))[quad];
    const float4 mk1 = ((const float4*)(nbs + (vA + 1) * 16))[quad];

    // edge chunk (kc=4) gathered fp32 -> bf16 inline (each edge row used ~once)
    FragU ef0, ef1;
    {
      const float4* ep0 = (const float4*)(edge + (size_t)e0 * 32 + quad * 8);
      const float4* ep1 = (const float4*)(edge + (size_t)e1 * 32 + quad * 8);
      float4 xa = ep0[0], xb = ep0[1], ya = ep1[0], yb = ep1[1];
      ef0.u[0]=f2bf(xa.x); ef0.u[1]=f2bf(xa.y); ef0.u[2]=f2bf(xa.z); ef0.u[3]=f2bf(xa.w);
      ef0.u[4]=f2bf(xb.x); ef0.u[5]=f2bf(xb.y); ef0.u[6]=f2bf(xb.z); ef0.u[7]=f2bf(xb.w);
      ef1.u[0]=f2bf(ya.x); ef1.u[1]=f2bf(ya.y); ef1.u[2]=f2bf(ya.z); ef1.u[3]=f2bf(ya.w);
      ef1.u[4]=f2bf(yb.x); ef1.u[5]=f2bf(yb.y); ef1.u[6]=f2bf(yb.z); ef1.u[7]=f2bf(yb.w);
    }

    f32x4 acc0[8] = {};
    f32x4 acc1[8] = {};
    const unsigned short* r0 = vfbf + (size_t)a0 * 128 + quad * 8;
    const unsigned short* r1 = vfbf + (size_t)a1 * 128 + quad * 8;
#pragma unroll
    for (int kc = 0; kc < 4; kc++){        // vertex-feature part of the row
      FragU fa, fb;
      fa.u = *(const ushort8v*)(r0 + kc * 32);
      fb.u = *(const ushort8v*)(r1 + kc * 32);
#pragma unroll
      for (int nc = 0; nc < 8; nc++){
        FragU bf_;
        bf_.u = *(const ushort8v*)(w1f + ((kc * 8 + nc) * 64 + lane) * 8);
        acc0[nc] = __builtin_amdgcn_mfma_f32_16x16x32_bf16(fa.b, bf_.b, acc0[nc], 0, 0, 0);
        acc1[nc] = __builtin_amdgcn_mfma_f32_16x16x32_bf16(fb.b, bf_.b, acc1[nc], 0, 0, 0);
      }
    }
#pragma unroll
    for (int nc = 0; nc < 8; nc++){        // edge part (kc=4)
      FragU bf_;
      bf_.u = *(const ushort8v*)(w1f + ((4 * 8 + nc) * 64 + lane) * 8);
      acc0[nc] = __builtin_amdgcn_mfma_f32_16x16x32_bf16(ef0.b, bf_.b, acc0[nc], 0, 0, 0);
      acc1[nc] = __builtin_amdgcn_mfma_f32_16x16x32_bf16(ef1.b, bf_.b, acc1[nc], 0, 0, 0);
    }

    // epilogue: +b1, GELU, mask-weight, reduce over 16 neighbor rows, nl -> LDS
#pragma unroll
    for (int pv = 0; pv < 2; ++pv){
      const float4 mk = pv ? mk1 : mk0;
      const int row = wid * 4 + it * 2 + pv;
#pragma unroll
      for (int nc = 0; nc < 8; nc++){
        f32x4 acc = pv ? acc1[nc] : acc0[nc];
        float s;
        {
          float g0 = gelu_f(acc[0] + b1v[nc]);
          float g1 = gelu_f(acc[1] + b1v[nc]);
          float g2 = gelu_f(acc[2] + b1v[nc]);
          float g3 = gelu_f(acc[3] + b1v[nc]);
          s = g0 * mk.x + g1 * mk.y + g2 * mk.z + g3 * mk.w;
        }
        s += __shfl_xor(s, 16, 64);
        s += __shfl_xor(s, 32, 64);
        if ((nc >> 1) == quad)
          nl_lds[row * NLSTR + nc * 16 + col] = f2bf(s);
      }
    }
  }
  __syncthreads();

  // ---------------- stage 2: wave wid computes output cols [wid*32, wid*32+32) --------
  const int nc0 = 2 * wid;
  const float th = logf(lamda[0] / (float)lval[0] + 1.0f);
  const float al = alpha[0];

  f32x4 acc2[2] = {};
#pragma unroll
  for (int kc = 0; kc < 8; kc++){
    FragU a;
    if (kc < 4) a.u = *(const ushort8v*)(nl_lds + col * NLSTR + kc * 32 + quad * 8);
    else        a.u = *(const ushort8v*)(vfbf + (size_t)(v0 + col) * 128 + (kc - 4) * 32 + quad * 8);
#pragma unroll
    for (int p = 0; p < 2; p++){
      FragU bf_;
      bf_.u = *(const ushort8v*)(w2f + ((kc * 8 + nc0 + p) * 64 + lane) * 8);
      acc2[p] = __builtin_amdgcn_mfma_f32_16x16x32_bf16(a.b, bf_.b, acc2[p], 0, 0, 0);
    }
  }

  float sup[2][4];
#pragma unroll
  for (int p = 0; p < 2; p++){
    const int d = (nc0 + p) * 16 + col;
    const float bb = b2[d];
#pragma unroll
    for (int r = 0; r < 4; r++){
      const int vtx = v0 + quad * 4 + r;
      float hi = acc2[p][r] + bb;
      float s = (1.f - al) * hi + al * h0[vtx * 128 + d];
      sup[p][r] = s;
      sup_lds[(quad * 4 + r) * NLSTR + d] = f2bf(s);
    }
  }
  __syncthreads();

  f32x4 acc3[2] = {};
#pragma unroll
  for (int kc = 0; kc < 4; kc++){
    FragU a;
    a.u = *(const ushort8v*)(sup_lds + col * NLSTR + kc * 32 + quad * 8);
#pragma unroll
    for (int p = 0; p < 2; p++){
      FragU bf_;
      bf_.u = *(const ushort8v*)(w3f + ((kc * 8 + nc0 + p) * 64 + lane) * 8);
      acc3[p] = __builtin_amdgcn_mfma_f32_16x16x32_bf16(a.b, bf_.b, acc3[p], 0, 0, 0);
    }
  }

#pragma unroll
  for (int p = 0; p < 2; p++){
    const int d = (nc0 + p) * 16 + col;
    const float bb = b3[d];
#pragma unroll
    for (int r = 0; r < 4; r++){
      const int vtx = v0 + quad * 4 + r;
      out[vtx * 128 + d] = th * (acc3[p][r] + bb) + (1.f - th) * sup[p][r]
                         + vf[vtx * 128 + d];
    }
  }
}

extern "C" void kernel_launch(void* const* d_in, const int* in_sizes, int n_in,
                              void* d_out, int out_size, void* d_ws, size_t ws_size,
                              hipStream_t stream)
{
  const float* vfp  = (const float*)d_in[0];
  const int*   aadj = (const int*)d_in[1];
  const int*   badj = (const int*)d_in[2];
  const float* h0   = (const float*)d_in[3];
  const float* lam  = (const float*)d_in[4];
  const float* alp  = (const float*)d_in[5];
  const int*   lv   = (const int*)d_in[6];
  const float* edge = (const float*)d_in[7];
  // d_in[8] vertex_mask: unused by the reference math
  const float* nbs  = (const float*)d_in[9];
  const float* W1   = (const float*)d_in[10];
  const float* b1   = (const float*)d_in[11];
  const float* W2   = (const float*)d_in[12];
  const float* b2   = (const float*)d_in[13];
  const float* W3   = (const float*)d_in[14];
  const float* b3   = (const float*)d_in[15];
  float* out = (float*)d_out;

  // ws layout (ushorts): w1f [0,20480) | w2f [20480,53248) | w3f [53248,69632)
  //                      | vfbf [69632, 69632+2097152)   -> 4,333,568 bytes total
  unsigned short* w1f  = (unsigned short*)d_ws;
  unsigned short* w2f  = w1f + 20480;
  unsigned short* w3f  = w2f + 32768;
  unsigned short* vfbf = w3f + 16384;

  prep_kernel<<<1058, 256, 0, stream>>>(vfp, W1, W2, W3, vfbf, w1f, w2f, w3f);
  fused_kernel<<<1024, 256, 0, stream>>>(vfbf, vfp, aadj, badj, edge, nbs, h0,
                                         w1f, w2f, w3f, b1, b2, b3, lam, alp, lv, out);
}

// Round 3
// 153.259 us; speedup vs baseline: 1.6310x; 1.6310x over previous
//
#include <hip/hip_runtime.h>
#include <hip/hip_bf16.h>
#include <math.h>

// Problem constants: B=32 V=512 K=16 D=128 E=32 NE=8192 -> BV=16384 vertices
#define NLSTR 136   // LDS row stride (ushorts) for 16x128 tiles

typedef __bf16 bf16x8 __attribute__((ext_vector_type(8)));
typedef float f32x4 __attribute__((ext_vector_type(4)));
typedef unsigned short ushort8v __attribute__((ext_vector_type(8)));

union FragU { ushort8v u; bf16x8 b; };

static __device__ inline unsigned short f2bf(float f){
  unsigned u = __float_as_uint(f);
  u += 0x7fffu + ((u >> 16) & 1u);   // RNE
  return (unsigned short)(u >> 16);
}

// tanh-form GELU via sigmoid: x * sigmoid(1.59577(x + 0.044715 x^3))
static __device__ inline float gelu_f(float x){
  float u = x * x;
  float p = fmaf(u, 0.07135481283f, 1.5957691216f);
  float t = x * p;
  float e = __builtin_amdgcn_exp2f(t * -1.44269504f);
  return x * __builtin_amdgcn_rcpf(1.0f + e);
}

// ---------------- prep: bf16 vertex table + fragment-order bf16 weights ----------------
// w?f layout: frag (kc*8+nc) is 64 lanes x 8 elems contiguous: [((kc*8+nc)*64+lane)*8+j]
//   element j of lane (quad*16+col) = W[(nc*16+col)*rowlen + kc*32 + quad*8 + j]
__global__ __launch_bounds__(256) void prep_kernel(
    const float* __restrict__ vf, const float* __restrict__ W1,
    const float* __restrict__ W2, const float* __restrict__ W3,
    unsigned short* __restrict__ vfbf, unsigned short* __restrict__ w1f,
    unsigned short* __restrict__ w2f, unsigned short* __restrict__ w3f)
{
  int t = blockIdx.x * 256 + threadIdx.x;
  if (t < 262144){                       // 16384*128 / 8
    const float4* src = (const float4*)vf;
    float4 x = src[t * 2], y = src[t * 2 + 1];
    ushort8v o;
    o[0]=f2bf(x.x); o[1]=f2bf(x.y); o[2]=f2bf(x.z); o[3]=f2bf(x.w);
    o[4]=f2bf(y.x); o[5]=f2bf(y.y); o[6]=f2bf(y.z); o[7]=f2bf(y.w);
    *(ushort8v*)(vfbf + t * 8) = o;
    return;
  }
  int t2 = t - 262144;
  const float* W; unsigned short* O; int rowlen;
  if (t2 < 2560)      { W = W1; O = w1f; rowlen = 160; }             // 5kc x 8nc
  else if (t2 < 6656) { t2 -= 2560; W = W2; O = w2f; rowlen = 256; } // 8kc x 8nc
  else if (t2 < 8704) { t2 -= 6656; W = W3; O = w3f; rowlen = 128; } // 4kc x 8nc
  else return;
  int fragid = t2 >> 6, lane = t2 & 63;
  int kc = fragid >> 3, nc = fragid & 7, col = lane & 15, quad = lane >> 4;
  const float* s = W + (nc * 16 + col) * rowlen + kc * 32 + quad * 8;
  unsigned short* d = O + t2 * 8;
#pragma unroll
  for (int j = 0; j < 8; j++) d[j] = f2bf(s[j]);
}

// ---------------- fused: gather + W1 GEMM + GELU + K-sum + W2 + support + W3 + combine ----
// grid 1024 x 256thr. Block = 16 vertices. Stage1: wave wid owns vertices wid*4..wid*4+3,
// ONE vertex per iteration (acc[8] = 32 regs -> no spill; R2's pair version spilled 200MB).
// Stage2: all 4 waves N-split the 128 output columns (2 nc-chunks each).
__global__ __launch_bounds__(256) void fused_kernel(
    const unsigned short* __restrict__ vfbf, const float* __restrict__ vf,
    const int* __restrict__ aadj, const int* __restrict__ badj,
    const float* __restrict__ edge, const float* __restrict__ nbs,
    const float* __restrict__ h0,
    const unsigned short* __restrict__ w1f, const unsigned short* __restrict__ w2f,
    const unsigned short* __restrict__ w3f,
    const float* __restrict__ b1, const float* __restrict__ b2, const float* __restrict__ b3,
    const float* __restrict__ lamda, const float* __restrict__ alpha,
    const int* __restrict__ lval,
    float* __restrict__ out)
{
  __shared__ __align__(16) unsigned short nl_lds[16 * NLSTR];
  __shared__ __align__(16) unsigned short sup_lds[16 * NLSTR];
  const int wid  = threadIdx.x >> 6;
  const int lane = threadIdx.x & 63;
  const int col  = lane & 15;
  const int quad = lane >> 4;
  const int v0   = blockIdx.x * 16;

  float b1v[8];
#pragma unroll
  for (int nc = 0; nc < 8; nc++) b1v[nc] = b1[nc * 16 + col];

  // ---------------- stage 1: one vertex per iteration ----------------
  for (int it = 0; it < 4; ++it){
    const int vA = v0 + wid * 4 + it;
    const int a  = aadj[vA * 16 + col];     // neighbor row for lane's col (replicated per quad)
    const int e  = badj[vA * 16 + col];
    const float4 mk = ((const float4*)(nbs + vA * 16))[quad];

    // edge chunk (kc=4) gathered fp32 -> bf16 inline (each edge row used ~once)
    FragU ef;
    {
      const float4* ep = (const float4*)(edge + (size_t)e * 32 + quad * 8);
      float4 xa = ep[0], xb = ep[1];
      ef.u[0]=f2bf(xa.x); ef.u[1]=f2bf(xa.y); ef.u[2]=f2bf(xa.z); ef.u[3]=f2bf(xa.w);
      ef.u[4]=f2bf(xb.x); ef.u[5]=f2bf(xb.y); ef.u[6]=f2bf(xb.z); ef.u[7]=f2bf(xb.w);
    }

    f32x4 acc[8] = {};
    const unsigned short* r = vfbf + (size_t)a * 128 + quad * 8;
#pragma unroll
    for (int kc = 0; kc < 4; kc++){        // vertex-feature part of the row
      FragU fa;
      fa.u = *(const ushort8v*)(r + kc * 32);
#pragma unroll
      for (int nc = 0; nc < 8; nc++){
        FragU bf_;
        bf_.u = *(const ushort8v*)(w1f + ((kc * 8 + nc) * 64 + lane) * 8);
        acc[nc] = __builtin_amdgcn_mfma_f32_16x16x32_bf16(fa.b, bf_.b, acc[nc], 0, 0, 0);
      }
    }
#pragma unroll
    for (int nc = 0; nc < 8; nc++){        // edge part (kc=4)
      FragU bf_;
      bf_.u = *(const ushort8v*)(w1f + ((4 * 8 + nc) * 64 + lane) * 8);
      acc[nc] = __builtin_amdgcn_mfma_f32_16x16x32_bf16(ef.b, bf_.b, acc[nc], 0, 0, 0);
    }

    // epilogue: +b1, GELU, mask-weight, reduce over 16 neighbor rows, nl -> LDS
    const int row = wid * 4 + it;
#pragma unroll
    for (int nc = 0; nc < 8; nc++){
      float g0 = gelu_f(acc[nc][0] + b1v[nc]);
      float g1 = gelu_f(acc[nc][1] + b1v[nc]);
      float g2 = gelu_f(acc[nc][2] + b1v[nc]);
      float g3 = gelu_f(acc[nc][3] + b1v[nc]);
      float s  = g0 * mk.x + g1 * mk.y + g2 * mk.z + g3 * mk.w;
      s += __shfl_xor(s, 16, 64);
      s += __shfl_xor(s, 32, 64);
      if ((nc >> 1) == quad)
        nl_lds[row * NLSTR + nc * 16 + col] = f2bf(s);
    }
  }
  __syncthreads();

  // ---------------- stage 2: wave wid computes output cols [wid*32, wid*32+32) --------
  const int nc0 = 2 * wid;
  const float th = logf(lamda[0] / (float)lval[0] + 1.0f);
  const float al = alpha[0];

  f32x4 acc2[2] = {};
#pragma unroll
  for (int kc = 0; kc < 8; kc++){
    FragU a;
    if (kc < 4) a.u = *(const ushort8v*)(nl_lds + col * NLSTR + kc * 32 + quad * 8);
    else        a.u = *(const ushort8v*)(vfbf + (size_t)(v0 + col) * 128 + (kc - 4) * 32 + quad * 8);
#pragma unroll
    for (int p = 0; p < 2; p++){
      FragU bf_;
      bf_.u = *(const ushort8v*)(w2f + ((kc * 8 + nc0 + p) * 64 + lane) * 8);
      acc2[p] = __builtin_amdgcn_mfma_f32_16x16x32_bf16(a.b, bf_.b, acc2[p], 0, 0, 0);
    }
  }

  float sup[2][4];
#pragma unroll
  for (int p = 0; p < 2; p++){
    const int d = (nc0 + p) * 16 + col;
    const float bb = b2[d];
#pragma unroll
    for (int r = 0; r < 4; r++){
      const int vtx = v0 + quad * 4 + r;
      float hi = acc2[p][r] + bb;
      float s = (1.f - al) * hi + al * h0[vtx * 128 + d];
      sup[p][r] = s;
      sup_lds[(quad * 4 + r) * NLSTR + d] = f2bf(s);
    }
  }
  __syncthreads();

  f32x4 acc3[2] = {};
#pragma unroll
  for (int kc = 0; kc < 4; kc++){
    FragU a;
    a.u = *(const ushort8v*)(sup_lds + col * NLSTR + kc * 32 + quad * 8);
#pragma unroll
    for (int p = 0; p < 2; p++){
      FragU bf_;
      bf_.u = *(const ushort8v*)(w3f + ((kc * 8 + nc0 + p) * 64 + lane) * 8);
      acc3[p] = __builtin_amdgcn_mfma_f32_16x16x32_bf16(a.b, bf_.b, acc3[p], 0, 0, 0);
    }
  }

#pragma unroll
  for (int p = 0; p < 2; p++){
    const int d = (nc0 + p) * 16 + col;
    const float bb = b3[d];
#pragma unroll
    for (int r = 0; r < 4; r++){
      const int vtx = v0 + quad * 4 + r;
      out[vtx * 128 + d] = th * (acc3[p][r] + bb) + (1.f - th) * sup[p][r]
                         + vf[vtx * 128 + d];
    }
  }
}

extern "C" void kernel_launch(void* const* d_in, const int* in_sizes, int n_in,
                              void* d_out, int out_size, void* d_ws, size_t ws_size,
                              hipStream_t stream)
{
  const float* vfp  = (const float*)d_in[0];
  const int*   aadj = (const int*)d_in[1];
  const int*   badj = (const int*)d_in[2];
  const float* h0   = (const float*)d_in[3];
  const float* lam  = (const float*)d_in[4];
  const float* alp  = (const float*)d_in[5];
  const int*   lv   = (const int*)d_in[6];
  const float* edge = (const float*)d_in[7];
  // d_in[8] vertex_mask: unused by the reference math
  const float* nbs  = (const float*)d_in[9];
  const float* W1   = (const float*)d_in[10];
  const float* b1   = (const float*)d_in[11];
  const float* W2   = (const float*)d_in[12];
  const float* b2   = (const float*)d_in[13];
  const float* W3   = (const float*)d_in[14];
  const float* b3   = (const float*)d_in[15];
  float* out = (float*)d_out;

  // ws layout (ushorts): w1f [0,20480) | w2f [20480,53248) | w3f [53248,69632)
  //                      | vfbf [69632, 69632+2097152)
  unsigned short* w1f  = (unsigned short*)d_ws;
  unsigned short* w2f  = w1f + 20480;
  unsigned short* w3f  = w2f + 32768;
  unsigned short* vfbf = w3f + 16384;

  prep_kernel<<<1058, 256, 0, stream>>>(vfp, W1, W2, W3, vfbf, w1f, w2f, w3f);
  fused_kernel<<<1024, 256, 0, stream>>>(vfbf, vfp, aadj, badj, edge, nbs, h0,
                                         w1f, w2f, w3f, b1, b2, b3, lam, alp, lv, out);
}

// Round 4
// 149.815 us; speedup vs baseline: 1.6685x; 1.0230x over previous
//
#include <hip/hip_runtime.h>
#include <hip/hip_bf16.h>
#include <math.h>

// Problem constants: B=32 V=512 K=16 D=128 E=32 NE=8192 -> BV=16384 vertices
// edge table is (B*NE)=262144 rows x 32 floats = 32 MB (gathered, kept fp32, cvt inline)
#define NLSTR 136   // LDS row stride (ushorts) for 16x128 tiles

typedef __bf16 bf16x8 __attribute__((ext_vector_type(8)));
typedef float f32x4 __attribute__((ext_vector_type(4)));
typedef float f32x16 __attribute__((ext_vector_type(16)));
typedef unsigned short ushort8v __attribute__((ext_vector_type(8)));

union FragU { ushort8v u; bf16x8 b; };

static __device__ inline unsigned short f2bf(float f){
  unsigned u = __float_as_uint(f);
  u += 0x7fffu + ((u >> 16) & 1u);   // RNE
  return (unsigned short)(u >> 16);
}
static __device__ inline float bf2f(unsigned short u){
  return __uint_as_float(((unsigned)u) << 16);
}

// tanh-form GELU (max err ~3e-4 vs exact erf-GELU; sigmoid-1.702 form is too coarse
// because the masked 16-neighbor sum accumulates systematic error)
static __device__ inline float gelu_f(float x){
  float u = x * x;
  float p = fmaf(u, 0.07135481283f, 1.5957691216f);
  float t = x * p;
  float e = __builtin_amdgcn_exp2f(t * -1.44269504f);
  return x * __builtin_amdgcn_rcpf(1.0f + e);
}

// ---------------- prep: bf16 vertex table + fragment-order bf16 weights ----------------
// w1f: 32x32x16 B-frags. frag (kc*4+nc2), elem j of lane: W1[(nc2*32+(lane&31))*160 + kc*16 + (lane>>5)*8 + j]
// w2f/w3f: 16x16x32 B-frags. frag (kc*8+nc), elem j of lane: W[(nc*16+(lane&15))*rowlen + kc*32 + (lane>>4)*8 + j]
__global__ __launch_bounds__(256) void prep_kernel(
    const float* __restrict__ vf, const float* __restrict__ W1,
    const float* __restrict__ W2, const float* __restrict__ W3,
    unsigned short* __restrict__ vfbf, unsigned short* __restrict__ w1f,
    unsigned short* __restrict__ w2f, unsigned short* __restrict__ w3f)
{
  int t = blockIdx.x * 256 + threadIdx.x;
  if (t < 262144){                       // 16384*128 / 8
    const float4* src = (const float4*)vf;
    float4 x = src[t * 2], y = src[t * 2 + 1];
    ushort8v o;
    o[0]=f2bf(x.x); o[1]=f2bf(x.y); o[2]=f2bf(x.z); o[3]=f2bf(x.w);
    o[4]=f2bf(y.x); o[5]=f2bf(y.y); o[6]=f2bf(y.z); o[7]=f2bf(y.w);
    *(ushort8v*)(vfbf + t * 8) = o;
    return;
  }
  int t2 = t - 262144;
  const float* s;
  unsigned short* d;
  if (t2 < 2560){                        // w1f: 10kc x 4nc2, 32x32x16 layout
    int fragid = t2 >> 6, lane = t2 & 63;
    int kc = fragid >> 2, nc2 = fragid & 3, n = lane & 31, h = lane >> 5;
    s = W1 + (nc2 * 32 + n) * 160 + kc * 16 + h * 8;
    d = w1f + t2 * 8;
  } else if (t2 < 6656){                 // w2f: 8kc x 8nc, 16x16x32 layout
    int t3 = t2 - 2560;
    int fragid = t3 >> 6, lane = t3 & 63;
    int kc = fragid >> 3, nc = fragid & 7, col = lane & 15, quad = lane >> 4;
    s = W2 + (nc * 16 + col) * 256 + kc * 32 + quad * 8;
    d = w2f + t3 * 8;
  } else if (t2 < 8704){                 // w3f: 4kc x 8nc, 16x16x32 layout
    int t3 = t2 - 6656;
    int fragid = t3 >> 6, lane = t3 & 63;
    int kc = fragid >> 3, nc = fragid & 7, col = lane & 15, quad = lane >> 4;
    s = W3 + (nc * 16 + col) * 128 + kc * 32 + quad * 8;
    d = w3f + t3 * 8;
  } else return;
#pragma unroll
  for (int j = 0; j < 8; j++) d[j] = f2bf(s[j]);
}

// ---------------- fused ----------------
// grid 1024 x 256thr. Block = 16 vertices. Stage1: wave wid owns vertices wid*4..+3,
// TWO vertices per MFMA via 32x32x16 (M=32: rows 0-15 = vertex A's neighbors, 16-31 = B's).
// Stage2: waves N-split the 128 output columns (16x16x32 path, as R3).
__global__ __launch_bounds__(256) void fused_kernel(
    const unsigned short* __restrict__ vfbf,
    const int* __restrict__ aadj, const int* __restrict__ badj,
    const float* __restrict__ edge, const float* __restrict__ nbs,
    const float* __restrict__ h0,
    const unsigned short* __restrict__ w1f, const unsigned short* __restrict__ w2f,
    const unsigned short* __restrict__ w3f,
    const float* __restrict__ b1, const float* __restrict__ b2, const float* __restrict__ b3,
    const float* __restrict__ lamda, const float* __restrict__ alpha,
    const int* __restrict__ lval,
    float* __restrict__ out)
{
  __shared__ __align__(16) unsigned short nl_lds[16 * NLSTR];
  __shared__ __align__(16) unsigned short sup_lds[16 * NLSTR];
  const int wid  = threadIdx.x >> 6;
  const int lane = threadIdx.x & 63;
  const int n32  = lane & 31;          // stage1: output col within nc2 chunk / A row m
  const int h    = lane >> 5;          // stage1: k-half selector
  const int nb   = lane & 15;          // neighbor slot
  const int vsel = (lane >> 4) & 1;    // 0: vertex A rows (m<16), 1: vertex B rows
  const int col  = lane & 15;          // stage2
  const int quad = lane >> 4;          // stage2
  const int v0   = blockIdx.x * 16;

  float b1v[4];
#pragma unroll
  for (int nc2 = 0; nc2 < 4; nc2++) b1v[nc2] = b1[nc2 * 32 + n32];

  const ushort8v* w1v = (const ushort8v*)w1f;
  const float4*   nbs4 = (const float4*)nbs;

  // ---------------- stage 1: one vertex PAIR per iteration ----------------
  for (int itp = 0; itp < 2; ++itp){
    const int vA  = v0 + wid * 4 + itp * 2;
    const int vtx = vA + vsel;
    const int a = aadj[vtx * 16 + nb];
    const int e = badj[vtx * 16 + nb];

    // all A-side gathers issued upfront (latency hiding)
    ushort8v av[8];
    const ushort8v* arow = (const ushort8v*)(vfbf + (size_t)a * 128 + h * 8);
#pragma unroll
    for (int kc = 0; kc < 8; kc++) av[kc] = arow[kc * 2];
    float4 e0a = *(const float4*)(edge + (size_t)e * 32 + h * 8);
    float4 e0b = *(const float4*)(edge + (size_t)e * 32 + h * 8 + 4);
    float4 e1a = *(const float4*)(edge + (size_t)e * 32 + 16 + h * 8);
    float4 e1b = *(const float4*)(edge + (size_t)e * 32 + 16 + h * 8 + 4);
    // masks (needed in epilogue; issue early)
    const float4 mAlo = nbs4[vA * 4 + h],       mAhi = nbs4[vA * 4 + 2 + h];
    const float4 mBlo = nbs4[(vA + 1) * 4 + h], mBhi = nbs4[(vA + 1) * 4 + 2 + h];

    FragU ef[2];
    ef[0].u[0]=f2bf(e0a.x); ef[0].u[1]=f2bf(e0a.y); ef[0].u[2]=f2bf(e0a.z); ef[0].u[3]=f2bf(e0a.w);
    ef[0].u[4]=f2bf(e0b.x); ef[0].u[5]=f2bf(e0b.y); ef[0].u[6]=f2bf(e0b.z); ef[0].u[7]=f2bf(e0b.w);
    ef[1].u[0]=f2bf(e1a.x); ef[1].u[1]=f2bf(e1a.y); ef[1].u[2]=f2bf(e1a.z); ef[1].u[3]=f2bf(e1a.w);
    ef[1].u[4]=f2bf(e1b.x); ef[1].u[5]=f2bf(e1b.y); ef[1].u[6]=f2bf(e1b.z); ef[1].u[7]=f2bf(e1b.w);

    f32x16 acc[4] = {};
#pragma unroll
    for (int kc = 0; kc < 10; kc++){
      FragU fa;
      if (kc < 8) fa.u = av[kc];
      else        fa.u = ef[kc - 8].u;
#pragma unroll
      for (int nc2 = 0; nc2 < 4; nc2++){
        FragU bf_;
        bf_.u = w1v[(kc * 4 + nc2) * 64 + lane];
        acc[nc2] = __builtin_amdgcn_mfma_f32_32x32x16_bf16(fa.b, bf_.b, acc[nc2], 0, 0, 0);
      }
    }

    // epilogue: +b1, GELU, mask-weight, reduce 16 neighbor rows per vertex.
    // C row = (reg&3) + 8*(reg>>2) + 4*h; regs 0-7 -> vertex A rows, 8-15 -> vertex B.
    const int row = wid * 4 + itp * 2;
#pragma unroll
    for (int nc2 = 0; nc2 < 4; nc2++){
      const float bb = b1v[nc2];
      f32x16 ac = acc[nc2];
      float sA = gelu_f(ac[0] + bb) * mAlo.x + gelu_f(ac[1] + bb) * mAlo.y
               + gelu_f(ac[2] + bb) * mAlo.z + gelu_f(ac[3] + bb) * mAlo.w
               + gelu_f(ac[4] + bb) * mAhi.x + gelu_f(ac[5] + bb) * mAhi.y
               + gelu_f(ac[6] + bb) * mAhi.z + gelu_f(ac[7] + bb) * mAhi.w;
      float sB = gelu_f(ac[8] + bb) * mBlo.x + gelu_f(ac[9] + bb) * mBlo.y
               + gelu_f(ac[10] + bb) * mBlo.z + gelu_f(ac[11] + bb) * mBlo.w
               + gelu_f(ac[12] + bb) * mBhi.x + gelu_f(ac[13] + bb) * mBhi.y
               + gelu_f(ac[14] + bb) * mBhi.z + gelu_f(ac[15] + bb) * mBhi.w;
      sA += __shfl_xor(sA, 32, 64);
      sB += __shfl_xor(sB, 32, 64);
      if (h == 0) nl_lds[row * NLSTR + nc2 * 32 + n32] = f2bf(sA);
      else        nl_lds[(row + 1) * NLSTR + nc2 * 32 + n32] = f2bf(sB);
    }
  }
  __syncthreads();

  // ---------------- stage 2: wave wid computes output cols [wid*32, wid*32+32) --------
  const int nc0 = 2 * wid;
  const float th = logf(lamda[0] / (float)lval[0] + 1.0f);
  const float al = alpha[0];

  f32x4 acc2[2] = {};
#pragma unroll
  for (int kc = 0; kc < 8; kc++){
    FragU a;
    if (kc < 4) a.u = *(const ushort8v*)(nl_lds + col * NLSTR + kc * 32 + quad * 8);
    else        a.u = *(const ushort8v*)(vfbf + (size_t)(v0 + col) * 128 + (kc - 4) * 32 + quad * 8);
#pragma unroll
    for (int p = 0; p < 2; p++){
      FragU bf_;
      bf_.u = *(const ushort8v*)(w2f + ((kc * 8 + nc0 + p) * 64 + lane) * 8);
      acc2[p] = __builtin_amdgcn_mfma_f32_16x16x32_bf16(a.b, bf_.b, acc2[p], 0, 0, 0);
    }
  }

  float sup[2][4];
#pragma unroll
  for (int p = 0; p < 2; p++){
    const int d = (nc0 + p) * 16 + col;
    const float bb = b2[d];
#pragma unroll
    for (int r = 0; r < 4; r++){
      const int vtx = v0 + quad * 4 + r;
      float hi = acc2[p][r] + bb;
      float s = (1.f - al) * hi + al * h0[vtx * 128 + d];
      sup[p][r] = s;
      sup_lds[(quad * 4 + r) * NLSTR + d] = f2bf(s);
    }
  }
  __syncthreads();

  f32x4 acc3[2] = {};
#pragma unroll
  for (int kc = 0; kc < 4; kc++){
    FragU a;
    a.u = *(const ushort8v*)(sup_lds + col * NLSTR + kc * 32 + quad * 8);
#pragma unroll
    for (int p = 0; p < 2; p++){
      FragU bf_;
      bf_.u = *(const ushort8v*)(w3f + ((kc * 8 + nc0 + p) * 64 + lane) * 8);
      acc3[p] = __builtin_amdgcn_mfma_f32_16x16x32_bf16(a.b, bf_.b, acc3[p], 0, 0, 0);
    }
  }

#pragma unroll
  for (int p = 0; p < 2; p++){
    const int d = (nc0 + p) * 16 + col;
    const float bb = b3[d];
#pragma unroll
    for (int r = 0; r < 4; r++){
      const int vtx = v0 + quad * 4 + r;
      float res = bf2f(vfbf[(size_t)vtx * 128 + d]);   // residual via bf16 table (-4MB fetch)
      out[vtx * 128 + d] = th * (acc3[p][r] + bb) + (1.f - th) * sup[p][r] + res;
    }
  }
}

extern "C" void kernel_launch(void* const* d_in, const int* in_sizes, int n_in,
                              void* d_out, int out_size, void* d_ws, size_t ws_size,
                              hipStream_t stream)
{
  const float* vfp  = (const float*)d_in[0];
  const int*   aadj = (const int*)d_in[1];
  const int*   badj = (const int*)d_in[2];
  const float* h0   = (const float*)d_in[3];
  const float* lam  = (const float*)d_in[4];
  const float* alp  = (const float*)d_in[5];
  const int*   lv   = (const int*)d_in[6];
  const float* edge = (const float*)d_in[7];
  // d_in[8] vertex_mask: unused by the reference math
  const float* nbs  = (const float*)d_in[9];
  const float* W1   = (const float*)d_in[10];
  const float* b1   = (const float*)d_in[11];
  const float* W2   = (const float*)d_in[12];
  const float* b2   = (const float*)d_in[13];
  const float* W3   = (const float*)d_in[14];
  const float* b3   = (const float*)d_in[15];
  float* out = (float*)d_out;

  // ws layout (ushorts): w1f [0,20480) | w2f [20480,53248) | w3f [53248,69632)
  //                      | vfbf [69632, 69632+2097152)
  unsigned short* w1f  = (unsigned short*)d_ws;
  unsigned short* w2f  = w1f + 20480;
  unsigned short* w3f  = w2f + 32768;
  unsigned short* vfbf = w3f + 16384;

  prep_kernel<<<1058, 256, 0, stream>>>(vfp, W1, W2, W3, vfbf, w1f, w2f, w3f);
  fused_kernel<<<1024, 256, 0, stream>>>(vfbf, aadj, badj, edge, nbs, h0,
                                         w1f, w2f, w3f, b1, b2, b3, lam, alp, lv, out);
}